// Round 4
// baseline (271.864 us; speedup 1.0000x reference)
//
#include <hip/hip_runtime.h>
#include <math.h>

#define N_NODES 200000
#define N_EDGES 6400000
#define N_GRAPHS 128

// ---- binned (counting-sort) path parameters ----
#define BSZ   196                 // nodes per bucket
#define NBK   1021                // ceil-ish: 1020*196=199920, bucket 1020 holds 80 nodes
#define NBKP  1024                // padded stride for countMat
#define EBLK  2000                // phase-A blocks
#define EPB   (N_EDGES / EBLK)    // 3200 edges per phase-A block (800 int4s)

static __device__ __forceinline__ unsigned bkt_of(unsigned node) { return node / (unsigned)BSZ; }

// ============================================================
// Fast path: counting-sort by dst bucket + LDS aggregation
// ============================================================

// Phase A0: per-block histogram of dst buckets
__global__ void kA0_hist(const int* __restrict__ dst, unsigned* __restrict__ countMat) {
    __shared__ unsigned cnt[NBK];
    for (int t = threadIdx.x; t < NBK; t += blockDim.x) cnt[t] = 0;
    __syncthreads();
    const int4* d4 = (const int4*)(dst + blockIdx.x * EPB);
    for (int e = threadIdx.x; e < EPB / 4; e += blockDim.x) {
        int4 d = d4[e];
        atomicAdd(&cnt[bkt_of((unsigned)d.x)], 1u);
        atomicAdd(&cnt[bkt_of((unsigned)d.y)], 1u);
        atomicAdd(&cnt[bkt_of((unsigned)d.z)], 1u);
        atomicAdd(&cnt[bkt_of((unsigned)d.w)], 1u);
    }
    __syncthreads();
    for (int t = threadIdx.x; t < NBK; t += blockDim.x)
        countMat[blockIdx.x * NBKP + t] = cnt[t];
}

// Phase A-scan1: per bucket, exclusive scan over the EBLK block counts (in place),
// column sum -> colsum. One wave per bucket.
__global__ void kScanBlk(unsigned* __restrict__ mat, unsigned* __restrict__ colsum) {
    int bkt = blockIdx.x * 4 + (threadIdx.x >> 6);
    if (bkt >= NBK) return;
    int lane = threadIdx.x & 63;
    unsigned carry = 0;
    const int rounds = (EBLK + 63) / 64;
    for (int k = 0; k < rounds; ++k) {
        int blk = k * 64 + lane;
        unsigned v = (blk < EBLK) ? mat[blk * NBKP + bkt] : 0u;
        unsigned s = v;
        for (int off = 1; off < 64; off <<= 1) {
            unsigned u = __shfl_up(s, off);
            if (lane >= off) s += u;
        }
        if (blk < EBLK) mat[blk * NBKP + bkt] = carry + s - v;   // exclusive within column
        carry += __shfl(s, 63);
    }
    colsum[bkt] = carry;
}

// Phase A-scan2: exclusive scan over buckets -> bucketBase[NBK+1]  (1024 threads)
__global__ void kScanBkt(const unsigned* __restrict__ colsum, unsigned* __restrict__ bucketBase) {
    __shared__ unsigned wsum[16];
    int t = threadIdx.x;
    int lane = t & 63, w = t >> 6;
    unsigned v = (t < NBK) ? colsum[t] : 0u;
    unsigned s = v;
    for (int off = 1; off < 64; off <<= 1) {
        unsigned u = __shfl_up(s, off);
        if (lane >= off) s += u;
    }
    if (lane == 63) wsum[w] = s;
    __syncthreads();
    if (w == 0 && lane < 16) {
        int nw = blockDim.x >> 6;
        unsigned ws = (lane < nw) ? wsum[lane] : 0u;
        unsigned ss = ws;
        for (int off = 1; off < 16; off <<= 1) {
            unsigned u = __shfl_up(ss, off);
            if (lane >= off) ss += u;
        }
        wsum[lane] = ss - ws;  // exclusive wave prefix
    }
    __syncthreads();
    unsigned excl = s - v + wsum[w];
    if (t < NBK) bucketBase[t] = excl;
    if (t == NBK - 1) bucketBase[NBK] = excl + v;
}

// Phase A1: scatter packed edges (src<<8 | dst%196) into bucket-ordered array
__global__ void kA1_scatter(const int* __restrict__ src, const int* __restrict__ dst,
                            const unsigned* __restrict__ baseMat,
                            const unsigned* __restrict__ bucketBase,
                            unsigned* __restrict__ binned) {
    __shared__ unsigned cur[NBK];
    for (int t = threadIdx.x; t < NBK; t += blockDim.x)
        cur[t] = baseMat[blockIdx.x * NBKP + t] + bucketBase[t];
    __syncthreads();
    const int base_e = blockIdx.x * EPB;
    const int4* s4 = (const int4*)(src + base_e);
    const int4* d4 = (const int4*)(dst + base_e);
    for (int e = threadIdx.x; e < EPB / 4; e += blockDim.x) {
        int4 s = s4[e];
        int4 d = d4[e];
        unsigned b0 = bkt_of((unsigned)d.x), l0 = (unsigned)d.x - b0 * BSZ;
        unsigned b1 = bkt_of((unsigned)d.y), l1 = (unsigned)d.y - b1 * BSZ;
        unsigned b2 = bkt_of((unsigned)d.z), l2 = (unsigned)d.z - b2 * BSZ;
        unsigned b3 = bkt_of((unsigned)d.w), l3 = (unsigned)d.w - b3 * BSZ;
        unsigned p;
        p = atomicAdd(&cur[b0], 1u); binned[p] = ((unsigned)s.x << 8) | l0;
        p = atomicAdd(&cur[b1], 1u); binned[p] = ((unsigned)s.y << 8) | l1;
        p = atomicAdd(&cur[b2], 1u); binned[p] = ((unsigned)s.z << 8) | l2;
        p = atomicAdd(&cur[b3], 1u); binned[p] = ((unsigned)s.w << 8) | l3;
    }
}

// Phase B: deg (LDS histogram per bucket) -> dinv, xd
__global__ void __launch_bounds__(512)
kB_deg(const unsigned* __restrict__ binned, const unsigned* __restrict__ bucketBase,
       const float* __restrict__ x, float* __restrict__ dinv, float* __restrict__ xd) {
    __shared__ unsigned deg[BSZ];
    if (threadIdx.x < BSZ) deg[threadIdx.x] = 0;
    __syncthreads();
    int b = blockIdx.x;
    unsigned lo = bucketBase[b], hi = bucketBase[b + 1];
    const uint4* b4 = (const uint4*)binned;
    for (unsigned q = lo / 4 + threadIdx.x; q * 4 < hi; q += blockDim.x) {
        uint4 v = b4[q];
        unsigned e0 = q * 4;
        if (e0 >= lo && e0 + 3 < hi) {
            atomicAdd(&deg[v.x & 255u], 1u);
            atomicAdd(&deg[v.y & 255u], 1u);
            atomicAdd(&deg[v.z & 255u], 1u);
            atomicAdd(&deg[v.w & 255u], 1u);
        } else {
            if (e0     >= lo && e0     < hi) atomicAdd(&deg[v.x & 255u], 1u);
            if (e0 + 1 >= lo && e0 + 1 < hi) atomicAdd(&deg[v.y & 255u], 1u);
            if (e0 + 2 >= lo && e0 + 2 < hi) atomicAdd(&deg[v.z & 255u], 1u);
            if (e0 + 3 >= lo && e0 + 3 < hi) atomicAdd(&deg[v.w & 255u], 1u);
        }
    }
    __syncthreads();
    if (threadIdx.x < BSZ) {
        int node = b * BSZ + threadIdx.x;
        if (node < N_NODES) {
            float di = rsqrtf((float)deg[threadIdx.x] + 1.0f);
            dinv[node] = di;
            xd[node] = x[node] * di;
        }
    }
}

// Phase C: t[dst] += xd[src] (LDS), then pair = {agg1*dinv, dinv}.  Prefetch-pipelined.
__global__ void __launch_bounds__(512)
kC_pass1(const unsigned* __restrict__ binned, const unsigned* __restrict__ bucketBase,
         const float* __restrict__ xd, const float* __restrict__ dinv,
         float2* __restrict__ pair) {
    __shared__ float tacc[BSZ];
    if (threadIdx.x < BSZ) tacc[threadIdx.x] = 0.0f;
    __syncthreads();
    int b = blockIdx.x;
    unsigned lo = bucketBase[b], hi = bucketBase[b + 1];
    const uint4* b4 = (const uint4*)binned;

    unsigned q = lo / 4 + threadIdx.x;
    bool act = (q * 4 < hi);
    uint4 v = act ? b4[q] : make_uint4(0, 0, 0, 0);
    while (act) {
        unsigned qn = q + blockDim.x;
        bool actn = (qn * 4 < hi);
        uint4 vn = actn ? b4[qn] : v;
        // issue all gathers (src always valid)
        float g0 = xd[v.x >> 8];
        float g1 = xd[v.y >> 8];
        float g2 = xd[v.z >> 8];
        float g3 = xd[v.w >> 8];
        unsigned e0 = q * 4;
        if (e0 >= lo && e0 + 3 < hi) {
            atomicAdd(&tacc[v.x & 255u], g0);
            atomicAdd(&tacc[v.y & 255u], g1);
            atomicAdd(&tacc[v.z & 255u], g2);
            atomicAdd(&tacc[v.w & 255u], g3);
        } else {
            if (e0     >= lo && e0     < hi) atomicAdd(&tacc[v.x & 255u], g0);
            if (e0 + 1 >= lo && e0 + 1 < hi) atomicAdd(&tacc[v.y & 255u], g1);
            if (e0 + 2 >= lo && e0 + 2 < hi) atomicAdd(&tacc[v.z & 255u], g2);
            if (e0 + 3 >= lo && e0 + 3 < hi) atomicAdd(&tacc[v.w & 255u], g3);
        }
        q = qn; act = actn; v = vn;
    }
    __syncthreads();
    if (threadIdx.x < BSZ) {
        int node = b * BSZ + threadIdx.x;
        if (node < N_NODES) {
            float di = dinv[node];
            float a = di * (tacc[threadIdx.x] + xd[node]);   // agg1 (self-loop folded)
            pair[node] = make_float2(a * di, di);
        }
    }
}

// Phase D: s1/s0 accumulate (LDS), finalize + per-graph pool.  Prefetch-pipelined.
__global__ void __launch_bounds__(512)
kD_pass2(const unsigned* __restrict__ binned, const unsigned* __restrict__ bucketBase,
         const float2* __restrict__ pair, const int* __restrict__ batch,
         float* __restrict__ gacc) {
    __shared__ float s1a[BSZ], s0a[BSZ];
    if (threadIdx.x < BSZ) { s1a[threadIdx.x] = 0.0f; s0a[threadIdx.x] = 0.0f; }
    __syncthreads();
    int b = blockIdx.x;
    unsigned lo = bucketBase[b], hi = bucketBase[b + 1];
    const uint4* b4 = (const uint4*)binned;

    unsigned q = lo / 4 + threadIdx.x;
    bool act = (q * 4 < hi);
    uint4 v = act ? b4[q] : make_uint4(0, 0, 0, 0);
    while (act) {
        unsigned qn = q + blockDim.x;
        bool actn = (qn * 4 < hi);
        uint4 vn = actn ? b4[qn] : v;
        float2 p0 = pair[v.x >> 8];
        float2 p1 = pair[v.y >> 8];
        float2 p2 = pair[v.z >> 8];
        float2 p3 = pair[v.w >> 8];
        unsigned e0 = q * 4;
        if (e0 >= lo && e0 + 3 < hi) {
            atomicAdd(&s1a[v.x & 255u], p0.x); atomicAdd(&s0a[v.x & 255u], p0.y);
            atomicAdd(&s1a[v.y & 255u], p1.x); atomicAdd(&s0a[v.y & 255u], p1.y);
            atomicAdd(&s1a[v.z & 255u], p2.x); atomicAdd(&s0a[v.z & 255u], p2.y);
            atomicAdd(&s1a[v.w & 255u], p3.x); atomicAdd(&s0a[v.w & 255u], p3.y);
        } else {
            if (e0     >= lo && e0     < hi) { atomicAdd(&s1a[v.x & 255u], p0.x); atomicAdd(&s0a[v.x & 255u], p0.y); }
            if (e0 + 1 >= lo && e0 + 1 < hi) { atomicAdd(&s1a[v.y & 255u], p1.x); atomicAdd(&s0a[v.y & 255u], p1.y); }
            if (e0 + 2 >= lo && e0 + 2 < hi) { atomicAdd(&s1a[v.z & 255u], p2.x); atomicAdd(&s0a[v.z & 255u], p2.y); }
            if (e0 + 3 >= lo && e0 + 3 < hi) { atomicAdd(&s1a[v.w & 255u], p3.x); atomicAdd(&s0a[v.w & 255u], p3.y); }
        }
        q = qn; act = actn; v = vn;
    }
    __syncthreads();
    if (threadIdx.x < 256) {
        int node = b * BSZ + threadIdx.x;
        float s1f = 0.0f, s0f = 0.0f;
        int g = 0;
        bool valid = (threadIdx.x < BSZ) && (node < N_NODES);
        if (valid) {
            float2 pr = pair[node];          // {agg1*di, di}
            float di = pr.y;
            s1f = di * (s1a[threadIdx.x] + pr.x);   // self-loop: + agg1*di
            s0f = di * (s0a[threadIdx.x] + di);     // self-loop: + di
            g = batch[node];
        }
        int g0 = __shfl(g, 0);
        bool uni = __all(valid && (g == g0));
        if (uni) {
            for (int off = 32; off; off >>= 1) {
                s1f += __shfl_down(s1f, off);
                s0f += __shfl_down(s0f, off);
            }
            if ((threadIdx.x & 63) == 0) {
                atomicAdd(&gacc[g0], s1f);
                atomicAdd(&gacc[N_GRAPHS + g0], s0f);
                atomicAdd(&gacc[2 * N_GRAPHS + g0], 64.0f);
            }
        } else if (valid) {
            atomicAdd(&gacc[g], s1f);
            atomicAdd(&gacc[N_GRAPHS + g], s0f);
            atomicAdd(&gacc[2 * N_GRAPHS + g], 1.0f);
        }
    }
}

// Final: pooled = (u*GS1 + v*GS0 + cnt*b2)/max(cnt,1); log_softmax over 8 classes
__global__ void k_final(const float* __restrict__ gacc,
                        const float* __restrict__ W1, const float* __restrict__ b1,
                        const float* __restrict__ W2, const float* __restrict__ b2,
                        float* __restrict__ out) {
    int g = threadIdx.x;
    if (g >= N_GRAPHS) return;
    float GS1 = gacc[g];
    float GS0 = gacc[N_GRAPHS + g];
    float cnt = gacc[2 * N_GRAPHS + g];
    float denom = fmaxf(cnt, 1.0f);
    float p[8];
    for (int k = 0; k < 8; ++k) {
        float u = 0.0f, v = 0.0f;
        for (int c = 0; c < 32; ++c) {
            u += W1[c] * W2[c * 8 + k];
            v += b1[c] * W2[c * 8 + k];
        }
        p[k] = (u * GS1 + v * GS0 + cnt * b2[k]) / denom;
    }
    float m = p[0];
    for (int k = 1; k < 8; ++k) m = fmaxf(m, p[k]);
    float s = 0.0f;
    for (int k = 0; k < 8; ++k) s += expf(p[k] - m);
    float l = logf(s);
    for (int k = 0; k < 8; ++k) out[g * 8 + k] = p[k] - m - l;
}

// ============================================================
// Fallback path: global-atomic pipeline (used if ws too small)
// ============================================================

__global__ void k_deg(const int* __restrict__ dst, float* __restrict__ deg) {
    const int4* d4 = (const int4*)dst;
    const int n4 = N_EDGES / 4;
    for (int e = blockIdx.x * blockDim.x + threadIdx.x; e < n4; e += gridDim.x * blockDim.x) {
        int4 d = d4[e];
        atomicAdd(&deg[d.x], 1.0f);
        atomicAdd(&deg[d.y], 1.0f);
        atomicAdd(&deg[d.z], 1.0f);
        atomicAdd(&deg[d.w], 1.0f);
    }
}

__global__ void k_dinv(const float* __restrict__ x, float* __restrict__ deg_dinv,
                       float* __restrict__ xd) {
    int i = blockIdx.x * blockDim.x + threadIdx.x;
    if (i < N_NODES) {
        float dinv = rsqrtf(deg_dinv[i] + 1.0f);
        deg_dinv[i] = dinv;
        xd[i] = x[i] * dinv;
    }
}

__global__ void k_pass1(const int* __restrict__ src, const int* __restrict__ dst,
                        const float* __restrict__ xd, float* __restrict__ t) {
    const int4* s4 = (const int4*)src;
    const int4* d4 = (const int4*)dst;
    const int n4 = N_EDGES / 4;
    for (int e = blockIdx.x * blockDim.x + threadIdx.x; e < n4; e += gridDim.x * blockDim.x) {
        int4 s = s4[e];
        int4 d = d4[e];
        atomicAdd(&t[d.x], xd[s.x]);
        atomicAdd(&t[d.y], xd[s.y]);
        atomicAdd(&t[d.z], xd[s.z]);
        atomicAdd(&t[d.w], xd[s.w]);
    }
}

__global__ void k_agg1(const float* __restrict__ dinv, const float* __restrict__ xd,
                       float* __restrict__ t, float2* __restrict__ pair) {
    int i = blockIdx.x * blockDim.x + threadIdx.x;
    if (i < N_NODES) {
        float di = dinv[i];
        float a = di * (t[i] + xd[i]);
        t[i] = a;
        pair[i] = make_float2(a * di, di);
    }
}

__global__ void k_pass2(const int* __restrict__ src, const int* __restrict__ dst,
                        const float2* __restrict__ pair,
                        float* __restrict__ s1, float* __restrict__ s0) {
    const int4* s4 = (const int4*)src;
    const int4* d4 = (const int4*)dst;
    const int n4 = N_EDGES / 4;
    for (int e = blockIdx.x * blockDim.x + threadIdx.x; e < n4; e += gridDim.x * blockDim.x) {
        int4 s = s4[e];
        int4 d = d4[e];
        float2 p0 = pair[s.x];
        float2 p1 = pair[s.y];
        float2 p2 = pair[s.z];
        float2 p3 = pair[s.w];
        atomicAdd(&s1[d.x], p0.x); atomicAdd(&s0[d.x], p0.y);
        atomicAdd(&s1[d.y], p1.x); atomicAdd(&s0[d.y], p1.y);
        atomicAdd(&s1[d.z], p2.x); atomicAdd(&s0[d.z], p2.y);
        atomicAdd(&s1[d.w], p3.x); atomicAdd(&s0[d.w], p3.y);
    }
}

__global__ void k_node2(const float* __restrict__ dinv, const float* __restrict__ agg1,
                        const float* __restrict__ s1, const float* __restrict__ s0,
                        const int* __restrict__ batch, float* __restrict__ gacc) {
    int i = blockIdx.x * blockDim.x + threadIdx.x;
    float s1f = 0.0f, s0f = 0.0f;
    int g = 0;
    bool valid = (i < N_NODES);
    if (valid) {
        float di = dinv[i];
        s1f = di * (s1[i] + agg1[i] * di);
        s0f = di * (s0[i] + di);
        g = batch[i];
    }
    int g0 = __shfl(g, 0);
    bool uni = __all(valid && (g == g0));
    if (uni) {
        for (int off = 32; off; off >>= 1) {
            s1f += __shfl_down(s1f, off);
            s0f += __shfl_down(s0f, off);
        }
        if ((threadIdx.x & 63) == 0) {
            atomicAdd(&gacc[g0], s1f);
            atomicAdd(&gacc[N_GRAPHS + g0], s0f);
            atomicAdd(&gacc[2 * N_GRAPHS + g0], 64.0f);
        }
    } else if (valid) {
        atomicAdd(&gacc[g], s1f);
        atomicAdd(&gacc[N_GRAPHS + g], s0f);
        atomicAdd(&gacc[2 * N_GRAPHS + g], 1.0f);
    }
}

// ---------------- launch ----------------

extern "C" void kernel_launch(void* const* d_in, const int* in_sizes, int n_in,
                              void* d_out, int out_size, void* d_ws, size_t ws_size,
                              hipStream_t stream) {
    const float* x     = (const float*)d_in[0];
    const int*   edge  = (const int*)d_in[1];   // int64 in ref; harness delivers int32
    const int*   batch = (const int*)d_in[2];
    const float* W1    = (const float*)d_in[3];
    const float* b1    = (const float*)d_in[4];
    const float* W2    = (const float*)d_in[5];
    const float* b2    = (const float*)d_in[6];
    float* out = (float*)d_out;

    const int* src = edge;
    const int* dst = edge + N_EDGES;

    const size_t o_binned = 0;
    const size_t o_cmat   = o_binned + (size_t)N_EDGES;
    const size_t o_colsum = o_cmat + (size_t)EBLK * NBKP;
    const size_t o_bbase  = o_colsum + NBKP;
    const size_t o_dinv   = o_bbase + NBKP;
    const size_t o_xd     = o_dinv + N_NODES;
    size_t o_pair         = o_xd + N_NODES;
    if (o_pair & 1) o_pair++;                    // 8B align for float2
    const size_t o_gacc   = o_pair + 2 * (size_t)N_NODES;
    const size_t need_u32 = o_gacc + 3 * N_GRAPHS;

    unsigned* ws_u = (unsigned*)d_ws;
    float*    ws_f = (float*)d_ws;

    if (ws_size >= need_u32 * 4) {
        // ---------- fast path ----------
        unsigned* binned     = ws_u + o_binned;
        unsigned* countMat   = ws_u + o_cmat;
        unsigned* colsum     = ws_u + o_colsum;
        unsigned* bucketBase = ws_u + o_bbase;
        float*    dinv       = ws_f + o_dinv;
        float*    xd         = ws_f + o_xd;
        float2*   pair       = (float2*)(ws_f + o_pair);
        float*    gacc       = ws_f + o_gacc;

        hipMemsetAsync(gacc, 0, 3 * N_GRAPHS * sizeof(float), stream);

        kA0_hist   <<<EBLK, 256, 0, stream>>>(dst, countMat);
        kScanBlk   <<<(NBK + 3) / 4, 256, 0, stream>>>(countMat, colsum);
        kScanBkt   <<<1, 1024, 0, stream>>>(colsum, bucketBase);
        kA1_scatter<<<EBLK, 256, 0, stream>>>(src, dst, countMat, bucketBase, binned);
        kB_deg     <<<NBK, 512, 0, stream>>>(binned, bucketBase, x, dinv, xd);
        kC_pass1   <<<NBK, 512, 0, stream>>>(binned, bucketBase, xd, dinv, pair);
        kD_pass2   <<<NBK, 512, 0, stream>>>(binned, bucketBase, pair, batch, gacc);
        k_final    <<<1, 128, 0, stream>>>(gacc, W1, b1, W2, b2, out);
    } else {
        // ---------- fallback: global-atomic path ----------
        float* dinv = ws_f;
        float* t    = ws_f + 1 * N_NODES;
        float* s1   = ws_f + 2 * N_NODES;
        float* s0   = ws_f + 3 * N_NODES;
        float* xd   = ws_f + 4 * N_NODES;
        float2* pair = (float2*)(ws_f + 5 * N_NODES);
        float* gacc = ws_f + 7 * N_NODES;

        hipMemsetAsync(ws_f, 0, (size_t)4 * N_NODES * sizeof(float), stream);
        hipMemsetAsync(gacc, 0, (size_t)3 * N_GRAPHS * sizeof(float), stream);

        const int EB = 2048, ET = 256;
        const int NB = (N_NODES + 255) / 256, NT = 256;

        k_deg  <<<EB, ET, 0, stream>>>(dst, dinv);
        k_dinv <<<NB, NT, 0, stream>>>(x, dinv, xd);
        k_pass1<<<EB, ET, 0, stream>>>(src, dst, xd, t);
        k_agg1 <<<NB, NT, 0, stream>>>(dinv, xd, t, pair);
        k_pass2<<<EB, ET, 0, stream>>>(src, dst, pair, s1, s0);
        k_node2<<<NB, NT, 0, stream>>>(dinv, t, s1, s0, batch, gacc);
        k_final<<<1, 128, 0, stream>>>(gacc, W1, b1, W2, b2, out);
    }
}

// Round 5
// 259.143 us; speedup vs baseline: 1.0491x; 1.0491x over previous
//
#include <hip/hip_runtime.h>
#include <math.h>

#define N_NODES 200000
#define N_EDGES 6400000
#define N_GRAPHS 128
#define NI4     (N_EDGES / 4)     // 1,600,000 int4/uint4 elements

// ---- counting-sort parameters ----
#define BSZ   196                 // nodes per bucket
#define NBK   1021                // 1020*196=199920; bucket 1020 holds 80 nodes
#define NBKP  1024                // padded stride for countMat
#define EBLK  800                 // phase-A blocks
#define EPB   (N_EDGES / EBLK)    // 8000 edges / block
#define EPB4  (EPB / 4)           // 2000 int4 / block

static __device__ __forceinline__ unsigned bkt_of(unsigned node) { return node / (unsigned)BSZ; }

// ============================================================
// Phase A: counting sort of edges by dst bucket
// ============================================================

__global__ void __launch_bounds__(512)
kA0_hist(const int* __restrict__ dst, unsigned* __restrict__ countMat) {
    __shared__ unsigned cnt[NBK];
    for (int t = threadIdx.x; t < NBK; t += 512) cnt[t] = 0;
    __syncthreads();
    const int4* d4 = (const int4*)(dst + blockIdx.x * EPB);
    for (int e = threadIdx.x; e < EPB4; e += 512) {
        int4 d = d4[e];
        atomicAdd(&cnt[bkt_of((unsigned)d.x)], 1u);
        atomicAdd(&cnt[bkt_of((unsigned)d.y)], 1u);
        atomicAdd(&cnt[bkt_of((unsigned)d.z)], 1u);
        atomicAdd(&cnt[bkt_of((unsigned)d.w)], 1u);
    }
    __syncthreads();
    for (int t = threadIdx.x; t < NBK; t += 512)
        countMat[blockIdx.x * NBKP + t] = cnt[t];
}

// per bucket: exclusive scan over EBLK block counts (in place); column sum -> colsum
__global__ void kScanBlk(unsigned* __restrict__ mat, unsigned* __restrict__ colsum) {
    int bkt = blockIdx.x * 4 + (threadIdx.x >> 6);
    if (bkt >= NBK) return;
    int lane = threadIdx.x & 63;
    unsigned carry = 0;
    const int rounds = (EBLK + 63) / 64;
    for (int k = 0; k < rounds; ++k) {
        int blk = k * 64 + lane;
        unsigned v = (blk < EBLK) ? mat[blk * NBKP + bkt] : 0u;
        unsigned s = v;
        for (int off = 1; off < 64; off <<= 1) {
            unsigned u = __shfl_up(s, off);
            if (lane >= off) s += u;
        }
        if (blk < EBLK) mat[blk * NBKP + bkt] = carry + s - v;
        carry += __shfl(s, 63);
    }
    colsum[bkt] = carry;
}

// exclusive scan over buckets -> bucketBase[NBK+1]  (1024 threads)
__global__ void kScanBkt(const unsigned* __restrict__ colsum, unsigned* __restrict__ bucketBase) {
    __shared__ unsigned wsum[16];
    int t = threadIdx.x;
    int lane = t & 63, w = t >> 6;
    unsigned v = (t < NBK) ? colsum[t] : 0u;
    unsigned s = v;
    for (int off = 1; off < 64; off <<= 1) {
        unsigned u = __shfl_up(s, off);
        if (lane >= off) s += u;
    }
    if (lane == 63) wsum[w] = s;
    __syncthreads();
    if (w == 0 && lane < 16) {
        unsigned ws = wsum[lane];
        unsigned ss = ws;
        for (int off = 1; off < 16; off <<= 1) {
            unsigned u = __shfl_up(ss, off);
            if (lane >= off) ss += u;
        }
        wsum[lane] = ss - ws;
    }
    __syncthreads();
    unsigned excl = s - v + wsum[w];
    if (t < NBK) bucketBase[t] = excl;
    if (t == NBK - 1) bucketBase[NBK] = excl + v;
}

// scatter packed edges (src<<8 | dst_local) into bucket-ordered array
__global__ void __launch_bounds__(512)
kA1_scatter(const int* __restrict__ src, const int* __restrict__ dst,
            const unsigned* __restrict__ baseMat, const unsigned* __restrict__ bucketBase,
            unsigned* __restrict__ binned) {
    __shared__ unsigned cur[NBK];
    for (int t = threadIdx.x; t < NBK; t += 512)
        cur[t] = baseMat[blockIdx.x * NBKP + t] + bucketBase[t];
    __syncthreads();
    const int base_e = blockIdx.x * EPB;
    const int4* s4 = (const int4*)(src + base_e);
    const int4* d4 = (const int4*)(dst + base_e);
    for (int e = threadIdx.x; e < EPB4; e += 512) {
        int4 s = s4[e];
        int4 d = d4[e];
        unsigned b0 = bkt_of((unsigned)d.x), l0 = (unsigned)d.x - b0 * BSZ;
        unsigned b1 = bkt_of((unsigned)d.y), l1 = (unsigned)d.y - b1 * BSZ;
        unsigned b2 = bkt_of((unsigned)d.z), l2 = (unsigned)d.z - b2 * BSZ;
        unsigned b3 = bkt_of((unsigned)d.w), l3 = (unsigned)d.w - b3 * BSZ;
        unsigned p;
        p = atomicAdd(&cur[b0], 1u); binned[p] = ((unsigned)s.x << 8) | l0;
        p = atomicAdd(&cur[b1], 1u); binned[p] = ((unsigned)s.y << 8) | l1;
        p = atomicAdd(&cur[b2], 1u); binned[p] = ((unsigned)s.z << 8) | l2;
        p = atomicAdd(&cur[b3], 1u); binned[p] = ((unsigned)s.w << 8) | l3;
    }
}

// ============================================================
// Phase B: deg histogram -> dinv; write xd and dstPair={di, batch}
// ============================================================
__global__ void __launch_bounds__(512)
kB_deg(const unsigned* __restrict__ binned, const unsigned* __restrict__ bucketBase,
       const float* __restrict__ x, const int* __restrict__ batch,
       float* __restrict__ xd, float2* __restrict__ dstPair) {
    __shared__ unsigned deg[BSZ];
    if (threadIdx.x < BSZ) deg[threadIdx.x] = 0;
    __syncthreads();
    int b = blockIdx.x;
    unsigned lo = bucketBase[b], hi = bucketBase[b + 1];
    const uint4* b4 = (const uint4*)binned;
    unsigned lo4 = lo >> 2;

    uint4 v[4]; unsigned qs[4];
    #pragma unroll
    for (int k = 0; k < 4; ++k) {
        unsigned q = lo4 + threadIdx.x + k * 512u;
        qs[k] = q;
        unsigned qc = (q * 4u < hi) ? q : lo4;
        if (qc >= NI4) qc = 0;
        v[k] = b4[qc];
    }
    #pragma unroll
    for (int k = 0; k < 4; ++k) {
        unsigned e0 = qs[k] * 4u;
        uint4 w = v[k];
        if (e0 >= lo && e0 + 3 < hi) {
            atomicAdd(&deg[w.x & 255u], 1u);
            atomicAdd(&deg[w.y & 255u], 1u);
            atomicAdd(&deg[w.z & 255u], 1u);
            atomicAdd(&deg[w.w & 255u], 1u);
        } else {
            if (e0     >= lo && e0     < hi) atomicAdd(&deg[w.x & 255u], 1u);
            if (e0 + 1 >= lo && e0 + 1 < hi) atomicAdd(&deg[w.y & 255u], 1u);
            if (e0 + 2 >= lo && e0 + 2 < hi) atomicAdd(&deg[w.z & 255u], 1u);
            if (e0 + 3 >= lo && e0 + 3 < hi) atomicAdd(&deg[w.w & 255u], 1u);
        }
    }
    // residual (normally empty: max bucket < 4*512*4)
    for (unsigned q = lo4 + threadIdx.x + 4u * 512u; q * 4u < hi; q += 512u) {
        uint4 w = b4[q];
        unsigned e0 = q * 4u;
        if (e0     >= lo && e0     < hi) atomicAdd(&deg[w.x & 255u], 1u);
        if (e0 + 1 >= lo && e0 + 1 < hi) atomicAdd(&deg[w.y & 255u], 1u);
        if (e0 + 2 >= lo && e0 + 2 < hi) atomicAdd(&deg[w.z & 255u], 1u);
        if (e0 + 3 >= lo && e0 + 3 < hi) atomicAdd(&deg[w.w & 255u], 1u);
    }
    __syncthreads();
    if (threadIdx.x < BSZ) {
        int node = b * BSZ + threadIdx.x;
        if (node < N_NODES) {
            float di = rsqrtf((float)deg[threadIdx.x] + 1.0f);
            xd[node] = x[node] * di;
            dstPair[node] = make_float2(di, __int_as_float(batch[node]));
        }
    }
}

// ============================================================
// Phase C: t[dst] += xd[src] (LDS bins); write srcPair={agg1*di, di}
// ============================================================
__global__ void __launch_bounds__(512)
kC_pass1(const unsigned* __restrict__ binned, const unsigned* __restrict__ bucketBase,
         const float* __restrict__ xd, const float2* __restrict__ dstPair,
         float2* __restrict__ srcPair) {
    __shared__ float tacc[BSZ];
    if (threadIdx.x < BSZ) tacc[threadIdx.x] = 0.0f;
    __syncthreads();
    int b = blockIdx.x;
    unsigned lo = bucketBase[b], hi = bucketBase[b + 1];
    const uint4* b4 = (const uint4*)binned;
    unsigned lo4 = lo >> 2;

    uint4 v[4]; unsigned qs[4];
    #pragma unroll
    for (int k = 0; k < 4; ++k) {
        unsigned q = lo4 + threadIdx.x + k * 512u;
        qs[k] = q;
        unsigned qc = (q * 4u < hi) ? q : lo4;
        if (qc >= NI4) qc = 0;
        v[k] = b4[qc];
    }
    // issue all 16 gathers (clamped loads hold valid edges -> safe indices)
    float gx[4], gy[4], gz[4], gw[4];
    #pragma unroll
    for (int k = 0; k < 4; ++k) {
        gx[k] = xd[v[k].x >> 8];
        gy[k] = xd[v[k].y >> 8];
        gz[k] = xd[v[k].z >> 8];
        gw[k] = xd[v[k].w >> 8];
    }
    #pragma unroll
    for (int k = 0; k < 4; ++k) {
        unsigned e0 = qs[k] * 4u;
        uint4 w = v[k];
        if (e0 >= lo && e0 + 3 < hi) {
            atomicAdd(&tacc[w.x & 255u], gx[k]);
            atomicAdd(&tacc[w.y & 255u], gy[k]);
            atomicAdd(&tacc[w.z & 255u], gz[k]);
            atomicAdd(&tacc[w.w & 255u], gw[k]);
        } else {
            if (e0     >= lo && e0     < hi) atomicAdd(&tacc[w.x & 255u], gx[k]);
            if (e0 + 1 >= lo && e0 + 1 < hi) atomicAdd(&tacc[w.y & 255u], gy[k]);
            if (e0 + 2 >= lo && e0 + 2 < hi) atomicAdd(&tacc[w.z & 255u], gz[k]);
            if (e0 + 3 >= lo && e0 + 3 < hi) atomicAdd(&tacc[w.w & 255u], gw[k]);
        }
    }
    for (unsigned q = lo4 + threadIdx.x + 4u * 512u; q * 4u < hi; q += 512u) {
        uint4 w = b4[q];
        unsigned e0 = q * 4u;
        float a0 = xd[w.x >> 8], a1 = xd[w.y >> 8], a2 = xd[w.z >> 8], a3 = xd[w.w >> 8];
        if (e0     >= lo && e0     < hi) atomicAdd(&tacc[w.x & 255u], a0);
        if (e0 + 1 >= lo && e0 + 1 < hi) atomicAdd(&tacc[w.y & 255u], a1);
        if (e0 + 2 >= lo && e0 + 2 < hi) atomicAdd(&tacc[w.z & 255u], a2);
        if (e0 + 3 >= lo && e0 + 3 < hi) atomicAdd(&tacc[w.w & 255u], a3);
    }
    __syncthreads();
    if (threadIdx.x < BSZ) {
        int node = b * BSZ + threadIdx.x;
        if (node < N_NODES) {
            float di = dstPair[node].x;
            float a = di * (tacc[threadIdx.x] + xd[node]);   // agg1 (self-loop folded)
            srcPair[node] = make_float2(a * di, di);
        }
    }
}

// ============================================================
// Phase D: per-graph edge sums over RAW edge list (no sort needed)
// GS1_edge[g] += di[dst]*(agg1*di)[src];  GS0_edge[g] += di[dst]*di[src]
// ============================================================
#define DBLK  1000
#define DI4   (NI4 / DBLK)   // 1600 int4 per block

__global__ void __launch_bounds__(512)
kD_edges(const int* __restrict__ src, const int* __restrict__ dst,
         const float2* __restrict__ srcPair, const float2* __restrict__ dstPair,
         float* __restrict__ gacc) {
    __shared__ float wb[N_GRAPHS], zb[N_GRAPHS];
    if (threadIdx.x < N_GRAPHS) { wb[threadIdx.x] = 0.0f; zb[threadIdx.x] = 0.0f; }
    __syncthreads();
    const int base = blockIdx.x * DI4;
    const int4* s4 = (const int4*)src;
    const int4* d4 = (const int4*)dst;
    int4 sv[4], dv[4]; int idx[4];
    #pragma unroll
    for (int k = 0; k < 4; ++k) {
        int i = threadIdx.x + k * 512;
        idx[k] = i;
        int ic = (i < DI4) ? i : (DI4 - 1);
        sv[k] = s4[base + ic];
        dv[k] = d4[base + ic];
    }
    #pragma unroll
    for (int k = 0; k < 4; ++k) {
        float2 sp0 = srcPair[sv[k].x], dp0 = dstPair[dv[k].x];
        float2 sp1 = srcPair[sv[k].y], dp1 = dstPair[dv[k].y];
        float2 sp2 = srcPair[sv[k].z], dp2 = dstPair[dv[k].z];
        float2 sp3 = srcPair[sv[k].w], dp3 = dstPair[dv[k].w];
        if (idx[k] < DI4) {
            int g0 = __float_as_int(dp0.y), g1 = __float_as_int(dp1.y);
            int g2 = __float_as_int(dp2.y), g3 = __float_as_int(dp3.y);
            atomicAdd(&wb[g0], dp0.x * sp0.x); atomicAdd(&zb[g0], dp0.x * sp0.y);
            atomicAdd(&wb[g1], dp1.x * sp1.x); atomicAdd(&zb[g1], dp1.x * sp1.y);
            atomicAdd(&wb[g2], dp2.x * sp2.x); atomicAdd(&zb[g2], dp2.x * sp2.y);
            atomicAdd(&wb[g3], dp3.x * sp3.x); atomicAdd(&zb[g3], dp3.x * sp3.y);
        }
    }
    __syncthreads();
    if (threadIdx.x < N_GRAPHS) {
        atomicAdd(&gacc[threadIdx.x], wb[threadIdx.x]);
        atomicAdd(&gacc[N_GRAPHS + threadIdx.x], zb[threadIdx.x]);
    }
}

// ============================================================
// Phase N: self-loop terms + per-graph node counts
// ============================================================
__global__ void __launch_bounds__(512)
kN_nodes(const float2* __restrict__ srcPair, const int* __restrict__ batch,
         float* __restrict__ gacc) {
    int i = blockIdx.x * 512 + threadIdx.x;
    bool valid = (i < N_NODES);
    float s1 = 0.0f, s0 = 0.0f; int g = 0;
    if (valid) {
        float2 sp = srcPair[i];        // {agg1*di, di}
        s1 = sp.x * sp.y;              // agg1*di^2
        s0 = sp.y * sp.y;              // di^2
        g = batch[i];
    }
    int g0 = __shfl(g, 0);
    bool uni = __all(valid && (g == g0));
    if (uni) {
        for (int off = 32; off; off >>= 1) {
            s1 += __shfl_down(s1, off);
            s0 += __shfl_down(s0, off);
        }
        if ((threadIdx.x & 63) == 0) {
            atomicAdd(&gacc[g0], s1);
            atomicAdd(&gacc[N_GRAPHS + g0], s0);
            atomicAdd(&gacc[2 * N_GRAPHS + g0], 64.0f);
        }
    } else if (valid) {
        atomicAdd(&gacc[g], s1);
        atomicAdd(&gacc[N_GRAPHS + g], s0);
        atomicAdd(&gacc[2 * N_GRAPHS + g], 1.0f);
    }
}

// ============================================================
// Final: pooled -> log_softmax
// ============================================================
__global__ void k_final(const float* __restrict__ gacc,
                        const float* __restrict__ W1, const float* __restrict__ b1,
                        const float* __restrict__ W2, const float* __restrict__ b2,
                        float* __restrict__ out) {
    int g = threadIdx.x;
    if (g >= N_GRAPHS) return;
    float GS1 = gacc[g];
    float GS0 = gacc[N_GRAPHS + g];
    float cnt = gacc[2 * N_GRAPHS + g];
    float denom = fmaxf(cnt, 1.0f);
    float p[8];
    for (int k = 0; k < 8; ++k) {
        float u = 0.0f, v = 0.0f;
        for (int c = 0; c < 32; ++c) {
            u += W1[c] * W2[c * 8 + k];
            v += b1[c] * W2[c * 8 + k];
        }
        p[k] = (u * GS1 + v * GS0 + cnt * b2[k]) / denom;
    }
    float m = p[0];
    for (int k = 1; k < 8; ++k) m = fmaxf(m, p[k]);
    float s = 0.0f;
    for (int k = 0; k < 8; ++k) s += expf(p[k] - m);
    float l = logf(s);
    for (int k = 0; k < 8; ++k) out[g * 8 + k] = p[k] - m - l;
}

// ============================================================
// Fallback path: global-atomic pipeline (used if ws too small)
// ============================================================

__global__ void k_deg(const int* __restrict__ dst, float* __restrict__ deg) {
    const int4* d4 = (const int4*)dst;
    for (int e = blockIdx.x * blockDim.x + threadIdx.x; e < NI4; e += gridDim.x * blockDim.x) {
        int4 d = d4[e];
        atomicAdd(&deg[d.x], 1.0f);
        atomicAdd(&deg[d.y], 1.0f);
        atomicAdd(&deg[d.z], 1.0f);
        atomicAdd(&deg[d.w], 1.0f);
    }
}
__global__ void k_dinv(const float* __restrict__ x, float* __restrict__ deg_dinv,
                       float* __restrict__ xd) {
    int i = blockIdx.x * blockDim.x + threadIdx.x;
    if (i < N_NODES) {
        float dinv = rsqrtf(deg_dinv[i] + 1.0f);
        deg_dinv[i] = dinv;
        xd[i] = x[i] * dinv;
    }
}
__global__ void k_pass1(const int* __restrict__ src, const int* __restrict__ dst,
                        const float* __restrict__ xd, float* __restrict__ t) {
    const int4* s4 = (const int4*)src;
    const int4* d4 = (const int4*)dst;
    for (int e = blockIdx.x * blockDim.x + threadIdx.x; e < NI4; e += gridDim.x * blockDim.x) {
        int4 s = s4[e];
        int4 d = d4[e];
        atomicAdd(&t[d.x], xd[s.x]);
        atomicAdd(&t[d.y], xd[s.y]);
        atomicAdd(&t[d.z], xd[s.z]);
        atomicAdd(&t[d.w], xd[s.w]);
    }
}
__global__ void k_agg1(const float* __restrict__ dinv, const float* __restrict__ xd,
                       float* __restrict__ t, float2* __restrict__ pair) {
    int i = blockIdx.x * blockDim.x + threadIdx.x;
    if (i < N_NODES) {
        float di = dinv[i];
        float a = di * (t[i] + xd[i]);
        t[i] = a;
        pair[i] = make_float2(a * di, di);
    }
}
__global__ void k_pass2(const int* __restrict__ src, const int* __restrict__ dst,
                        const float2* __restrict__ pair,
                        float* __restrict__ s1, float* __restrict__ s0) {
    const int4* s4 = (const int4*)src;
    const int4* d4 = (const int4*)dst;
    for (int e = blockIdx.x * blockDim.x + threadIdx.x; e < NI4; e += gridDim.x * blockDim.x) {
        int4 s = s4[e];
        int4 d = d4[e];
        float2 p0 = pair[s.x], p1 = pair[s.y], p2 = pair[s.z], p3 = pair[s.w];
        atomicAdd(&s1[d.x], p0.x); atomicAdd(&s0[d.x], p0.y);
        atomicAdd(&s1[d.y], p1.x); atomicAdd(&s0[d.y], p1.y);
        atomicAdd(&s1[d.z], p2.x); atomicAdd(&s0[d.z], p2.y);
        atomicAdd(&s1[d.w], p3.x); atomicAdd(&s0[d.w], p3.y);
    }
}
__global__ void k_node2(const float* __restrict__ dinv, const float* __restrict__ agg1,
                        const float* __restrict__ s1, const float* __restrict__ s0,
                        const int* __restrict__ batch, float* __restrict__ gacc) {
    int i = blockIdx.x * blockDim.x + threadIdx.x;
    float s1f = 0.0f, s0f = 0.0f;
    int g = 0;
    bool valid = (i < N_NODES);
    if (valid) {
        float di = dinv[i];
        s1f = di * (s1[i] + agg1[i] * di);
        s0f = di * (s0[i] + di);
        g = batch[i];
    }
    int g0 = __shfl(g, 0);
    bool uni = __all(valid && (g == g0));
    if (uni) {
        for (int off = 32; off; off >>= 1) {
            s1f += __shfl_down(s1f, off);
            s0f += __shfl_down(s0f, off);
        }
        if ((threadIdx.x & 63) == 0) {
            atomicAdd(&gacc[g0], s1f);
            atomicAdd(&gacc[N_GRAPHS + g0], s0f);
            atomicAdd(&gacc[2 * N_GRAPHS + g0], 64.0f);
        }
    } else if (valid) {
        atomicAdd(&gacc[g], s1f);
        atomicAdd(&gacc[N_GRAPHS + g], s0f);
        atomicAdd(&gacc[2 * N_GRAPHS + g], 1.0f);
    }
}

// ---------------- launch ----------------

extern "C" void kernel_launch(void* const* d_in, const int* in_sizes, int n_in,
                              void* d_out, int out_size, void* d_ws, size_t ws_size,
                              hipStream_t stream) {
    const float* x     = (const float*)d_in[0];
    const int*   edge  = (const int*)d_in[1];
    const int*   batch = (const int*)d_in[2];
    const float* W1    = (const float*)d_in[3];
    const float* b1    = (const float*)d_in[4];
    const float* W2    = (const float*)d_in[5];
    const float* b2    = (const float*)d_in[6];
    float* out = (float*)d_out;

    const int* src = edge;
    const int* dst = edge + N_EDGES;

    // workspace layout (u32 units)
    const size_t o_binned  = 0;                                  // 6,400,000
    const size_t o_cmat    = o_binned + (size_t)N_EDGES;         // EBLK*NBKP = 819,200
    const size_t o_colsum  = o_cmat + (size_t)EBLK * NBKP;       // 1024
    const size_t o_bbase   = o_colsum + NBKP;                    // 1024
    const size_t o_xd      = o_bbase + NBKP;                     // 200,000
    const size_t o_dstPair = o_xd + N_NODES;                     // 400,000 (even offset)
    const size_t o_srcPair = o_dstPair + 2 * (size_t)N_NODES;    // 400,000
    const size_t o_gacc    = o_srcPair + 2 * (size_t)N_NODES;    // 384
    const size_t need_u32  = o_gacc + 3 * N_GRAPHS;

    unsigned* ws_u = (unsigned*)d_ws;
    float*    ws_f = (float*)d_ws;

    if (ws_size >= need_u32 * 4) {
        unsigned* binned     = ws_u + o_binned;
        unsigned* countMat   = ws_u + o_cmat;
        unsigned* colsum     = ws_u + o_colsum;
        unsigned* bucketBase = ws_u + o_bbase;
        float*    xd         = ws_f + o_xd;
        float2*   dstPair    = (float2*)(ws_f + o_dstPair);
        float2*   srcPair    = (float2*)(ws_f + o_srcPair);
        float*    gacc       = ws_f + o_gacc;

        hipMemsetAsync(gacc, 0, 3 * N_GRAPHS * sizeof(float), stream);

        kA0_hist   <<<EBLK, 512, 0, stream>>>(dst, countMat);
        kScanBlk   <<<(NBK + 3) / 4, 256, 0, stream>>>(countMat, colsum);
        kScanBkt   <<<1, 1024, 0, stream>>>(colsum, bucketBase);
        kA1_scatter<<<EBLK, 512, 0, stream>>>(src, dst, countMat, bucketBase, binned);
        kB_deg     <<<NBK, 512, 0, stream>>>(binned, bucketBase, x, batch, xd, dstPair);
        kC_pass1   <<<NBK, 512, 0, stream>>>(binned, bucketBase, xd, dstPair, srcPair);
        kD_edges   <<<DBLK, 512, 0, stream>>>(src, dst, srcPair, dstPair, gacc);
        kN_nodes   <<<(N_NODES + 511) / 512, 512, 0, stream>>>(srcPair, batch, gacc);
        k_final    <<<1, 128, 0, stream>>>(gacc, W1, b1, W2, b2, out);
    } else {
        float* dinv = ws_f;
        float* t    = ws_f + 1 * N_NODES;
        float* s1   = ws_f + 2 * N_NODES;
        float* s0   = ws_f + 3 * N_NODES;
        float* xd   = ws_f + 4 * N_NODES;
        float2* pair = (float2*)(ws_f + 6 * N_NODES);
        float* gacc = ws_f + 8 * N_NODES;

        hipMemsetAsync(ws_f, 0, (size_t)4 * N_NODES * sizeof(float), stream);
        hipMemsetAsync(gacc, 0, (size_t)3 * N_GRAPHS * sizeof(float), stream);

        const int EB = 2048, ET = 256;
        const int NB = (N_NODES + 255) / 256, NT = 256;

        k_deg  <<<EB, ET, 0, stream>>>(dst, dinv);
        k_dinv <<<NB, NT, 0, stream>>>(x, dinv, xd);
        k_pass1<<<EB, ET, 0, stream>>>(src, dst, xd, t);
        k_agg1 <<<NB, NT, 0, stream>>>(dinv, xd, t, pair);
        k_pass2<<<EB, ET, 0, stream>>>(src, dst, pair, s1, s0);
        k_node2<<<NB, NT, 0, stream>>>(dinv, t, s1, s0, batch, gacc);
        k_final<<<1, 128, 0, stream>>>(gacc, W1, b1, W2, b2, out);
    }
}

// Round 6
// 207.357 us; speedup vs baseline: 1.3111x; 1.2497x over previous
//
#include <hip/hip_runtime.h>
#include <math.h>

#define N_NODES 200000
#define N_EDGES 6400000
#define N_GRAPHS 128
#define NI4     (N_EDGES / 4)

// ---- coarse partition parameters ----
#define NBKC  128                 // coarse buckets
#define CBSZ  1568                // nodes per bucket: 128*1568 = 200704 >= 200000
#define CAP   51712               // slots per bucket (mean 50000, sigma~223 -> +7.7 sigma)
#define CHK   8000                // edges per partition block
#define CHK4  (CHK / 4)           // 2000 int4
#define PBLK  (N_EDGES / CHK)     // 800 partition blocks
#define NSUB  8                   // sub-blocks per bucket in B/C phases

static __device__ __forceinline__ unsigned bc_of(unsigned n) { return n / (unsigned)CBSZ; }

// ============================================================
// kP1: single-pass LDS-staged partition into 128 coarse buckets.
// packed word = (src << 11) | dst_local   (src<2^18, dst_local<1568<2^11)
// ============================================================
__global__ void __launch_bounds__(512)
kP1_partition(const int* __restrict__ src, const int* __restrict__ dst,
              unsigned* __restrict__ gcur, unsigned* __restrict__ binned) {
    __shared__ unsigned cnt[NBKC];    // counts
    __shared__ unsigned ofs[NBKC];    // exclusive offsets (stable)
    __shared__ unsigned cur[NBKC];    // scatter cursors
    __shared__ unsigned gofs[NBKC];   // global reserved bases
    __shared__ unsigned stage[CHK];   // 32 KB staging
    const int tid = threadIdx.x;
    if (tid < NBKC) cnt[tid] = 0;
    __syncthreads();

    const int base4 = blockIdx.x * CHK4;
    const int4* s4 = (const int4*)src;
    const int4* d4 = (const int4*)dst;
    int4 sv[4], dv[4];
    bool ok[4];
    #pragma unroll
    for (int k = 0; k < 4; ++k) {
        int e = tid + k * 512;
        ok[k] = (e < CHK4);
        int ec = ok[k] ? e : 0;
        sv[k] = s4[base4 + ec];
        dv[k] = d4[base4 + ec];
    }
    // histogram
    #pragma unroll
    for (int k = 0; k < 4; ++k) {
        if (ok[k]) {
            atomicAdd(&cnt[bc_of((unsigned)dv[k].x)], 1u);
            atomicAdd(&cnt[bc_of((unsigned)dv[k].y)], 1u);
            atomicAdd(&cnt[bc_of((unsigned)dv[k].z)], 1u);
            atomicAdd(&cnt[bc_of((unsigned)dv[k].w)], 1u);
        }
    }
    __syncthreads();
    // exclusive scan of 128 counts with one wave
    if (tid < 64) {
        unsigned v0 = cnt[tid];
        unsigned s0 = v0;
        for (int off = 1; off < 64; off <<= 1) {
            unsigned u = __shfl_up(s0, off);
            if (tid >= off) s0 += u;
        }
        unsigned tot0 = __shfl(s0, 63);
        unsigned v1 = cnt[64 + tid];
        unsigned s1 = v1;
        for (int off = 1; off < 64; off <<= 1) {
            unsigned u = __shfl_up(s1, off);
            if (tid >= off) s1 += u;
        }
        ofs[tid] = s0 - v0;
        ofs[64 + tid] = tot0 + s1 - v1;
    }
    __syncthreads();
    // reserve global ranges; init cursors
    if (tid < NBKC) {
        gofs[tid] = atomicAdd(&gcur[tid], cnt[tid]);
        cur[tid] = ofs[tid];
    }
    __syncthreads();
    // LDS scatter (bucket-ordered within chunk)
    #pragma unroll
    for (int k = 0; k < 4; ++k) {
        if (ok[k]) {
            unsigned p;
            unsigned b0 = bc_of((unsigned)dv[k].x), l0 = (unsigned)dv[k].x - b0 * CBSZ;
            unsigned b1 = bc_of((unsigned)dv[k].y), l1 = (unsigned)dv[k].y - b1 * CBSZ;
            unsigned b2 = bc_of((unsigned)dv[k].z), l2 = (unsigned)dv[k].z - b2 * CBSZ;
            unsigned b3 = bc_of((unsigned)dv[k].w), l3 = (unsigned)dv[k].w - b3 * CBSZ;
            p = atomicAdd(&cur[b0], 1u); stage[p] = ((unsigned)sv[k].x << 11) | l0;
            p = atomicAdd(&cur[b1], 1u); stage[p] = ((unsigned)sv[k].y << 11) | l1;
            p = atomicAdd(&cur[b2], 1u); stage[p] = ((unsigned)sv[k].z << 11) | l2;
            p = atomicAdd(&cur[b3], 1u); stage[p] = ((unsigned)sv[k].w << 11) | l3;
        }
    }
    __syncthreads();
    // coalesced flush: wave w handles buckets w, w+8, ...
    const int wave = tid >> 6, lane = tid & 63;
    for (int b = wave; b < NBKC; b += 8) {
        unsigned o = ofs[b];
        unsigned end = (b < NBKC - 1) ? ofs[b + 1] : (unsigned)CHK;
        unsigned c = end - o;
        unsigned gb = gofs[b];
        // overflow guard (should never trigger with CAP slack)
        if (gb >= (unsigned)CAP) continue;
        unsigned avail = (unsigned)CAP - gb;
        if (c > avail) c = avail;
        unsigned gbase = (unsigned)b * CAP + gb;
        for (unsigned i = lane; i < c; i += 64)
            binned[gbase + i] = stage[o + i];
    }
}

// ============================================================
// kB: degree histogram per bucket (8 sub-blocks, partial bins)
// ============================================================
__global__ void __launch_bounds__(512)
kB_deg(const unsigned* __restrict__ binned, const unsigned* __restrict__ gcur,
       unsigned* __restrict__ part) {
    __shared__ unsigned bins[CBSZ];
    const int tid = threadIdx.x;
    for (int l = tid; l < CBSZ; l += 512) bins[l] = 0;
    __syncthreads();
    const int bkt = blockIdx.x >> 3, sub = blockIdx.x & 7;
    unsigned cnt = gcur[bkt];
    if (cnt > (unsigned)CAP) cnt = CAP;
    unsigned per = (cnt + NSUB - 1) / NSUB;
    unsigned s = sub * per;
    unsigned e = s + per; if (e > cnt) e = cnt;
    const unsigned base = (unsigned)bkt * CAP;
    unsigned i = base + s + tid;
    const unsigned iend = base + e;
    for (; i + 3u * 512u < iend; i += 4u * 512u) {
        unsigned v0 = binned[i], v1 = binned[i + 512], v2 = binned[i + 1024], v3 = binned[i + 1536];
        atomicAdd(&bins[v0 & 2047u], 1u);
        atomicAdd(&bins[v1 & 2047u], 1u);
        atomicAdd(&bins[v2 & 2047u], 1u);
        atomicAdd(&bins[v3 & 2047u], 1u);
    }
    for (; i < iend; i += 512u) atomicAdd(&bins[binned[i] & 2047u], 1u);
    __syncthreads();
    unsigned* dst = part + (size_t)blockIdx.x * CBSZ;
    for (int l = tid; l < CBSZ; l += 512) dst[l] = bins[l];
}

// kRedB: deg = sum of 8 partials -> dinv; xd = x*dinv; dstPair = {dinv, batch}
__global__ void __launch_bounds__(512)
kRedB(const unsigned* __restrict__ part, const float* __restrict__ x,
      const int* __restrict__ batch, float* __restrict__ xd, float2* __restrict__ dstPair) {
    int n = blockIdx.x * 512 + threadIdx.x;
    if (n >= N_NODES) return;
    unsigned b = bc_of((unsigned)n);
    unsigned l = (unsigned)n - b * CBSZ;
    const unsigned* p = part + (size_t)(b * NSUB) * CBSZ + l;
    unsigned d = 0;
    #pragma unroll
    for (int j = 0; j < NSUB; ++j) d += p[(size_t)j * CBSZ];
    float di = rsqrtf((float)d + 1.0f);
    xd[n] = x[n] * di;
    dstPair[n] = make_float2(di, __int_as_float(batch[n]));
}

// ============================================================
// kC: pass1 t[dst] += xd[src] per bucket (float partial bins)
// ============================================================
__global__ void __launch_bounds__(512)
kC_pass1(const unsigned* __restrict__ binned, const unsigned* __restrict__ gcur,
         const float* __restrict__ xd, float* __restrict__ partF) {
    __shared__ float bins[CBSZ];
    const int tid = threadIdx.x;
    for (int l = tid; l < CBSZ; l += 512) bins[l] = 0.0f;
    __syncthreads();
    const int bkt = blockIdx.x >> 3, sub = blockIdx.x & 7;
    unsigned cnt = gcur[bkt];
    if (cnt > (unsigned)CAP) cnt = CAP;
    unsigned per = (cnt + NSUB - 1) / NSUB;
    unsigned s = sub * per;
    unsigned e = s + per; if (e > cnt) e = cnt;
    const unsigned base = (unsigned)bkt * CAP;
    unsigned i = base + s + tid;
    const unsigned iend = base + e;
    for (; i + 3u * 512u < iend; i += 4u * 512u) {
        unsigned v0 = binned[i], v1 = binned[i + 512], v2 = binned[i + 1024], v3 = binned[i + 1536];
        float g0 = xd[v0 >> 11], g1 = xd[v1 >> 11], g2 = xd[v2 >> 11], g3 = xd[v3 >> 11];
        atomicAdd(&bins[v0 & 2047u], g0);
        atomicAdd(&bins[v1 & 2047u], g1);
        atomicAdd(&bins[v2 & 2047u], g2);
        atomicAdd(&bins[v3 & 2047u], g3);
    }
    for (; i < iend; i += 512u) {
        unsigned v = binned[i];
        atomicAdd(&bins[v & 2047u], xd[v >> 11]);
    }
    __syncthreads();
    float* dst = partF + (size_t)blockIdx.x * CBSZ;
    for (int l = tid; l < CBSZ; l += 512) dst[l] = bins[l];
}

// kRedC: agg1 = di*(sum partials + xd); srcPair = {agg1*di, di};
// fused: self-loop terms + per-graph node counts -> gacc
__global__ void __launch_bounds__(512)
kRedC(const float* __restrict__ partF, const float* __restrict__ xd,
      const float2* __restrict__ dstPair, float2* __restrict__ srcPair,
      float* __restrict__ gacc) {
    int n = blockIdx.x * 512 + threadIdx.x;
    bool valid = (n < N_NODES);
    float s1 = 0.0f, s0 = 0.0f;
    int g = 0;
    if (valid) {
        unsigned b = bc_of((unsigned)n);
        unsigned l = (unsigned)n - b * CBSZ;
        const float* p = partF + (size_t)(b * NSUB) * CBSZ + l;
        float t = 0.0f;
        #pragma unroll
        for (int j = 0; j < NSUB; ++j) t += p[(size_t)j * CBSZ];
        float2 dp = dstPair[n];
        float di = dp.x;
        g = __float_as_int(dp.y);
        float a = di * (t + xd[n]);            // agg1 (self-loop folded)
        srcPair[n] = make_float2(a * di, di);
        s1 = a * di * di;                      // self-loop term for GS1
        s0 = di * di;                          // self-loop term for GS0
    }
    int g0 = __shfl(g, 0);
    bool uni = __all(valid && (g == g0));
    if (uni) {
        for (int off = 32; off; off >>= 1) {
            s1 += __shfl_down(s1, off);
            s0 += __shfl_down(s0, off);
        }
        if ((threadIdx.x & 63) == 0) {
            atomicAdd(&gacc[g0], s1);
            atomicAdd(&gacc[N_GRAPHS + g0], s0);
            atomicAdd(&gacc[2 * N_GRAPHS + g0], 64.0f);
        }
    } else if (valid) {
        atomicAdd(&gacc[g], s1);
        atomicAdd(&gacc[N_GRAPHS + g], s0);
        atomicAdd(&gacc[2 * N_GRAPHS + g], 1.0f);
    }
}

// ============================================================
// kD: per-graph edge sums over raw edge list
// ============================================================
#define DBLK  1000
#define DI4   (NI4 / DBLK)

__global__ void __launch_bounds__(512)
kD_edges(const int* __restrict__ src, const int* __restrict__ dst,
         const float2* __restrict__ srcPair, const float2* __restrict__ dstPair,
         float* __restrict__ gacc) {
    __shared__ float wb[N_GRAPHS], zb[N_GRAPHS];
    if (threadIdx.x < N_GRAPHS) { wb[threadIdx.x] = 0.0f; zb[threadIdx.x] = 0.0f; }
    __syncthreads();
    const int base = blockIdx.x * DI4;
    const int4* s4 = (const int4*)src;
    const int4* d4 = (const int4*)dst;
    int4 sv[4], dv[4]; int idx[4];
    #pragma unroll
    for (int k = 0; k < 4; ++k) {
        int i = threadIdx.x + k * 512;
        idx[k] = i;
        int ic = (i < DI4) ? i : (DI4 - 1);
        sv[k] = s4[base + ic];
        dv[k] = d4[base + ic];
    }
    #pragma unroll
    for (int k = 0; k < 4; ++k) {
        float2 sp0 = srcPair[sv[k].x], dp0 = dstPair[dv[k].x];
        float2 sp1 = srcPair[sv[k].y], dp1 = dstPair[dv[k].y];
        float2 sp2 = srcPair[sv[k].z], dp2 = dstPair[dv[k].z];
        float2 sp3 = srcPair[sv[k].w], dp3 = dstPair[dv[k].w];
        if (idx[k] < DI4) {
            int g0 = __float_as_int(dp0.y), g1 = __float_as_int(dp1.y);
            int g2 = __float_as_int(dp2.y), g3 = __float_as_int(dp3.y);
            atomicAdd(&wb[g0], dp0.x * sp0.x); atomicAdd(&zb[g0], dp0.x * sp0.y);
            atomicAdd(&wb[g1], dp1.x * sp1.x); atomicAdd(&zb[g1], dp1.x * sp1.y);
            atomicAdd(&wb[g2], dp2.x * sp2.x); atomicAdd(&zb[g2], dp2.x * sp2.y);
            atomicAdd(&wb[g3], dp3.x * sp3.x); atomicAdd(&zb[g3], dp3.x * sp3.y);
        }
    }
    __syncthreads();
    if (threadIdx.x < N_GRAPHS) {
        atomicAdd(&gacc[threadIdx.x], wb[threadIdx.x]);
        atomicAdd(&gacc[N_GRAPHS + threadIdx.x], zb[threadIdx.x]);
    }
}

// ============================================================
// Final: pooled -> log_softmax
// ============================================================
__global__ void k_final(const float* __restrict__ gacc,
                        const float* __restrict__ W1, const float* __restrict__ b1,
                        const float* __restrict__ W2, const float* __restrict__ b2,
                        float* __restrict__ out) {
    int g = threadIdx.x;
    if (g >= N_GRAPHS) return;
    float GS1 = gacc[g];
    float GS0 = gacc[N_GRAPHS + g];
    float cnt = gacc[2 * N_GRAPHS + g];
    float denom = fmaxf(cnt, 1.0f);
    float p[8];
    for (int k = 0; k < 8; ++k) {
        float u = 0.0f, v = 0.0f;
        for (int c = 0; c < 32; ++c) {
            u += W1[c] * W2[c * 8 + k];
            v += b1[c] * W2[c * 8 + k];
        }
        p[k] = (u * GS1 + v * GS0 + cnt * b2[k]) / denom;
    }
    float m = p[0];
    for (int k = 1; k < 8; ++k) m = fmaxf(m, p[k]);
    float s = 0.0f;
    for (int k = 0; k < 8; ++k) s += expf(p[k] - m);
    float l = logf(s);
    for (int k = 0; k < 8; ++k) out[g * 8 + k] = p[k] - m - l;
}

// ============================================================
// Fallback: global-atomic pipeline (used only if ws too small)
// ============================================================
__global__ void k_deg(const int* __restrict__ dst, float* __restrict__ deg) {
    const int4* d4 = (const int4*)dst;
    for (int e = blockIdx.x * blockDim.x + threadIdx.x; e < NI4; e += gridDim.x * blockDim.x) {
        int4 d = d4[e];
        atomicAdd(&deg[d.x], 1.0f); atomicAdd(&deg[d.y], 1.0f);
        atomicAdd(&deg[d.z], 1.0f); atomicAdd(&deg[d.w], 1.0f);
    }
}
__global__ void k_dinv(const float* __restrict__ x, float* __restrict__ deg_dinv,
                       float* __restrict__ xd) {
    int i = blockIdx.x * blockDim.x + threadIdx.x;
    if (i < N_NODES) {
        float dinv = rsqrtf(deg_dinv[i] + 1.0f);
        deg_dinv[i] = dinv;
        xd[i] = x[i] * dinv;
    }
}
__global__ void k_pass1(const int* __restrict__ src, const int* __restrict__ dst,
                        const float* __restrict__ xd, float* __restrict__ t) {
    const int4* s4 = (const int4*)src;
    const int4* d4 = (const int4*)dst;
    for (int e = blockIdx.x * blockDim.x + threadIdx.x; e < NI4; e += gridDim.x * blockDim.x) {
        int4 s = s4[e]; int4 d = d4[e];
        atomicAdd(&t[d.x], xd[s.x]); atomicAdd(&t[d.y], xd[s.y]);
        atomicAdd(&t[d.z], xd[s.z]); atomicAdd(&t[d.w], xd[s.w]);
    }
}
__global__ void k_agg1(const float* __restrict__ dinv, const float* __restrict__ xd,
                       float* __restrict__ t, float2* __restrict__ pair) {
    int i = blockIdx.x * blockDim.x + threadIdx.x;
    if (i < N_NODES) {
        float di = dinv[i];
        float a = di * (t[i] + xd[i]);
        t[i] = a;
        pair[i] = make_float2(a * di, di);
    }
}
__global__ void k_pass2(const int* __restrict__ src, const int* __restrict__ dst,
                        const float2* __restrict__ pair,
                        float* __restrict__ s1, float* __restrict__ s0) {
    const int4* s4 = (const int4*)src;
    const int4* d4 = (const int4*)dst;
    for (int e = blockIdx.x * blockDim.x + threadIdx.x; e < NI4; e += gridDim.x * blockDim.x) {
        int4 s = s4[e]; int4 d = d4[e];
        float2 p0 = pair[s.x], p1 = pair[s.y], p2 = pair[s.z], p3 = pair[s.w];
        atomicAdd(&s1[d.x], p0.x); atomicAdd(&s0[d.x], p0.y);
        atomicAdd(&s1[d.y], p1.x); atomicAdd(&s0[d.y], p1.y);
        atomicAdd(&s1[d.z], p2.x); atomicAdd(&s0[d.z], p2.y);
        atomicAdd(&s1[d.w], p3.x); atomicAdd(&s0[d.w], p3.y);
    }
}
__global__ void k_node2(const float* __restrict__ dinv, const float* __restrict__ agg1,
                        const float* __restrict__ s1, const float* __restrict__ s0,
                        const int* __restrict__ batch, float* __restrict__ gacc) {
    int i = blockIdx.x * blockDim.x + threadIdx.x;
    float s1f = 0.0f, s0f = 0.0f; int g = 0;
    bool valid = (i < N_NODES);
    if (valid) {
        float di = dinv[i];
        s1f = di * (s1[i] + agg1[i] * di);
        s0f = di * (s0[i] + di);
        g = batch[i];
    }
    int g0 = __shfl(g, 0);
    bool uni = __all(valid && (g == g0));
    if (uni) {
        for (int off = 32; off; off >>= 1) {
            s1f += __shfl_down(s1f, off);
            s0f += __shfl_down(s0f, off);
        }
        if ((threadIdx.x & 63) == 0) {
            atomicAdd(&gacc[g0], s1f);
            atomicAdd(&gacc[N_GRAPHS + g0], s0f);
            atomicAdd(&gacc[2 * N_GRAPHS + g0], 64.0f);
        }
    } else if (valid) {
        atomicAdd(&gacc[g], s1f);
        atomicAdd(&gacc[N_GRAPHS + g], s0f);
        atomicAdd(&gacc[2 * N_GRAPHS + g], 1.0f);
    }
}

// ---------------- launch ----------------

extern "C" void kernel_launch(void* const* d_in, const int* in_sizes, int n_in,
                              void* d_out, int out_size, void* d_ws, size_t ws_size,
                              hipStream_t stream) {
    const float* x     = (const float*)d_in[0];
    const int*   edge  = (const int*)d_in[1];
    const int*   batch = (const int*)d_in[2];
    const float* W1    = (const float*)d_in[3];
    const float* b1    = (const float*)d_in[4];
    const float* W2    = (const float*)d_in[5];
    const float* b2    = (const float*)d_in[6];
    float* out = (float*)d_out;

    const int* src = edge;
    const int* dst = edge + N_EDGES;

    // workspace layout (u32 units)
    const size_t o_binned  = 0;                                       // NBKC*CAP = 6,619,136
    const size_t o_gcur    = o_binned + (size_t)NBKC * CAP;           // 128
    const size_t o_part    = o_gcur + NBKC;                           // 1024*CBSZ = 1,605,632
    const size_t o_xd      = o_part + (size_t)NBKC * NSUB * CBSZ;     // 200,000
    const size_t o_dstPair = o_xd + N_NODES;                          // even offset
    const size_t o_srcPair = o_dstPair + 2 * (size_t)N_NODES;
    const size_t o_gacc    = o_srcPair + 2 * (size_t)N_NODES;
    const size_t need_u32  = o_gacc + 3 * N_GRAPHS;

    unsigned* ws_u = (unsigned*)d_ws;
    float*    ws_f = (float*)d_ws;

    if (ws_size >= need_u32 * 4) {
        unsigned* binned  = ws_u + o_binned;
        unsigned* gcur    = ws_u + o_gcur;
        unsigned* partU   = ws_u + o_part;
        float*    partF   = (float*)(ws_u + o_part);
        float*    xd      = ws_f + o_xd;
        float2*   dstPair = (float2*)(ws_f + o_dstPair);
        float2*   srcPair = (float2*)(ws_f + o_srcPair);
        float*    gacc    = ws_f + o_gacc;

        hipMemsetAsync(gcur, 0, NBKC * sizeof(unsigned), stream);
        hipMemsetAsync(gacc, 0, 3 * N_GRAPHS * sizeof(float), stream);

        kP1_partition<<<PBLK, 512, 0, stream>>>(src, dst, gcur, binned);
        kB_deg       <<<NBKC * NSUB, 512, 0, stream>>>(binned, gcur, partU);
        kRedB        <<<(N_NODES + 511) / 512, 512, 0, stream>>>(partU, x, batch, xd, dstPair);
        kC_pass1     <<<NBKC * NSUB, 512, 0, stream>>>(binned, gcur, xd, partF);
        kRedC        <<<(N_NODES + 511) / 512, 512, 0, stream>>>(partF, xd, dstPair, srcPair, gacc);
        kD_edges     <<<DBLK, 512, 0, stream>>>(src, dst, srcPair, dstPair, gacc);
        k_final      <<<1, 128, 0, stream>>>(gacc, W1, b1, W2, b2, out);
    } else {
        float* dinv = ws_f;
        float* t    = ws_f + 1 * N_NODES;
        float* s1   = ws_f + 2 * N_NODES;
        float* s0   = ws_f + 3 * N_NODES;
        float* xd   = ws_f + 4 * N_NODES;
        float2* pair = (float2*)(ws_f + 6 * N_NODES);
        float* gacc = ws_f + 8 * N_NODES;

        hipMemsetAsync(ws_f, 0, (size_t)4 * N_NODES * sizeof(float), stream);
        hipMemsetAsync(gacc, 0, (size_t)3 * N_GRAPHS * sizeof(float), stream);

        const int EB = 2048, ET = 256;
        const int NB = (N_NODES + 255) / 256, NT = 256;

        k_deg  <<<EB, ET, 0, stream>>>(dst, dinv);
        k_dinv <<<NB, NT, 0, stream>>>(x, dinv, xd);
        k_pass1<<<EB, ET, 0, stream>>>(src, dst, xd, t);
        k_agg1 <<<NB, NT, 0, stream>>>(dinv, xd, t, pair);
        k_pass2<<<EB, ET, 0, stream>>>(src, dst, pair, s1, s0);
        k_node2<<<NB, NT, 0, stream>>>(dinv, t, s1, s0, batch, gacc);
        k_final<<<1, 128, 0, stream>>>(gacc, W1, b1, W2, b2, out);
    }
}